// Round 2
// baseline (999.337 us; speedup 1.0000x reference)
//
#include <hip/hip_runtime.h>
#include <hip/hip_bf16.h>

#define FEAT 64

// ---------- bf16 helpers ----------
__device__ __forceinline__ float bflo2f(unsigned int u) {
    union { unsigned int u; float f; } v; v.u = u << 16; return v.f;
}
__device__ __forceinline__ float bfhi2f(unsigned int u) {
    union { unsigned int u; float f; } v; v.u = u & 0xffff0000u; return v.f;
}
__device__ __forceinline__ unsigned short f2bf(float f) {
    union { float f; unsigned int u; } v; v.f = f;
    unsigned int u = v.u;
    u += 0x7fffu + ((u >> 16) & 1u);   // round-to-nearest-even
    return (unsigned short)(u >> 16);
}

// ---------- 0. runtime dtype detection ----------
// flags[0] = 1 if float arrays are bf16, 0 if fp32
// flags[1] = 1 if edge_index is int64, 0 if int32
__global__ void detect_kernel(const unsigned short* __restrict__ xh,
                              const int* __restrict__ ei32,
                              int* __restrict__ flags) {
    __shared__ int cnt_bf, cnt_nz;
    int tid = threadIdx.x;
    if (tid == 0) { cnt_bf = 0; cnt_nz = 0; }
    __syncthreads();
    // float dtype probe: even 16-bit halves. bf16 data -> N(0,1) samples,
    // exponent in [110,132]. fp32 data -> low mantissa bits, ~9% in range.
    unsigned short h = xh[tid * 2];
    int e = (h >> 7) & 0xFF;
    if (e >= 110 && e <= 132) atomicAdd(&cnt_bf, 1);
    // index probe: odd 32-bit words. int64 -> high halves, all zero.
    if (ei32[tid * 2 + 1] != 0) atomicAdd(&cnt_nz, 1);
    __syncthreads();
    if (tid == 0) {
        flags[0] = (cnt_bf >= 128) ? 1 : 0;
        flags[1] = (cnt_nz < 8) ? 1 : 0;
    }
}

// ---------- 1. x -> f32 (4 elems/thread, both dtypes) ----------
__global__ void cvt_x_kernel(const void* __restrict__ in, float* __restrict__ out,
                             int n4, const int* __restrict__ flags) {
    int i = blockIdx.x * 256 + threadIdx.x;
    if (i >= n4) return;
    if (flags[0]) {
        uint2 v = ((const uint2*)in)[i];
        float4 o;
        o.x = bflo2f(v.x & 0xffffu); o.y = bfhi2f(v.x);
        o.z = bflo2f(v.y & 0xffffu); o.w = bfhi2f(v.y);
        ((float4*)out)[i] = o;
    } else {
        ((float4*)out)[i] = ((const float4*)in)[i];
    }
}

// ---------- 1b. small arrays (weights/bias) -> f32 ----------
__global__ void cvt_small_kernel(const void* __restrict__ in, float* __restrict__ out,
                                 int n, const int* __restrict__ flags) {
    int i = blockIdx.x * 256 + threadIdx.x;
    if (i >= n) return;
    out[i] = flags[0] ? bflo2f(((const unsigned short*)in)[i])
                      : ((const float*)in)[i];
}

// ---------- 2. degree histogram ----------
__global__ void degree_kernel(const int* __restrict__ ei32, int* __restrict__ cnt,
                              int E, int N, const int* __restrict__ flags) {
    int e = blockIdx.x * 256 + threadIdx.x;
    if (e >= E) return;
    int idx64 = flags[1];
    long off = idx64 ? (2L * ((long)E + e)) : ((long)E + e);
    int d = ei32[off];
    if ((unsigned)d < (unsigned)N) atomicAdd(&cnt[d], 1);
}

// ---------- 3. scatter-add: one wave per edge, lane = feature ----------
__global__ void scatter_kernel(const float* __restrict__ feat, const int* __restrict__ ei32,
                               float* __restrict__ agg, int E, int N,
                               const int* __restrict__ flags) {
    long gid = (long)blockIdx.x * 256 + threadIdx.x;
    long e = gid >> 6;
    if (e >= E) return;
    int f = (int)(gid & 63);
    int idx64 = flags[1];
    int s = idx64 ? ei32[2 * e]             : ei32[e];
    int d = idx64 ? ei32[2 * ((long)E + e)] : ei32[(long)E + e];
    if ((unsigned)s >= (unsigned)N || (unsigned)d >= (unsigned)N) return;
    atomicAdd(agg + (size_t)d * FEAT + f, feat[(size_t)s * FEAT + f]);
}

// ---------- 4. fused SAGE layer GEMM: out = relu([agg*inv | root] @ [Wa;Wr] + b) ----------
// block = 256 threads, tile = 64 rows x 64 cols, K = 128, all fp32
__global__ __launch_bounds__(256) void sage_gemm_kernel(
    const float* __restrict__ agg, const float* __restrict__ root, const int* __restrict__ cnt,
    const float* __restrict__ Wa, const float* __restrict__ Wr,
    const float* __restrict__ bias, float* __restrict__ out, int N) {

    __shared__ float A_l[64][128];       // unpadded: 32 KB (A col reads: 4-way conflict, acceptable)
    __shared__ float B_l[128 * 64];      // 32 KB

    int tid = threadIdx.x;
    int blk = blockIdx.x;

    // stage B = [Wa ; Wr], 2048 float4
    {
        const float4* wa4 = (const float4*)Wa;
        const float4* wr4 = (const float4*)Wr;
        float4* b4 = (float4*)B_l;
#pragma unroll
        for (int i = 0; i < 8; ++i) {
            int idx = tid + i * 256;
            b4[idx] = (idx < 1024) ? wa4[idx] : wr4[idx - 1024];
        }
    }
    // stage A: [agg*inv_cnt | root], 64 rows x 32 float4-chunks
#pragma unroll
    for (int i = 0; i < 8; ++i) {
        int idx = tid + i * 256;
        int r = idx >> 5;
        int c = idx & 31;
        int row = blk * 64 + r;
        float4 v = make_float4(0.f, 0.f, 0.f, 0.f);
        if (row < N) {
            if (c < 16) {
                int cc = cnt[row];
                float inv = 1.0f / (float)(cc > 0 ? cc : 1);
                float4 t = *(const float4*)(agg + (size_t)row * FEAT + c * 4);
                v.x = t.x * inv; v.y = t.y * inv; v.z = t.z * inv; v.w = t.w * inv;
            } else {
                v = *(const float4*)(root + (size_t)row * FEAT + (c - 16) * 4);
            }
        }
        *(float4*)&A_l[r][c * 4] = v;
    }
    __syncthreads();

    int cx = tid & 15;
    int ry = tid >> 4;
    int c0 = cx * 4;
    int r0 = ry * 4;

    float acc[4][4];
#pragma unroll
    for (int j = 0; j < 4; ++j)
#pragma unroll
        for (int i = 0; i < 4; ++i) acc[j][i] = 0.f;

#pragma unroll 8
    for (int k = 0; k < 128; ++k) {
        float4 b = *(const float4*)(B_l + k * 64 + c0);
        float a0 = A_l[r0 + 0][k];
        float a1 = A_l[r0 + 1][k];
        float a2 = A_l[r0 + 2][k];
        float a3 = A_l[r0 + 3][k];
        acc[0][0] += a0 * b.x; acc[0][1] += a0 * b.y; acc[0][2] += a0 * b.z; acc[0][3] += a0 * b.w;
        acc[1][0] += a1 * b.x; acc[1][1] += a1 * b.y; acc[1][2] += a1 * b.z; acc[1][3] += a1 * b.w;
        acc[2][0] += a2 * b.x; acc[2][1] += a2 * b.y; acc[2][2] += a2 * b.z; acc[2][3] += a2 * b.w;
        acc[3][0] += a3 * b.x; acc[3][1] += a3 * b.y; acc[3][2] += a3 * b.z; acc[3][3] += a3 * b.w;
    }

    float4 bb = *(const float4*)(bias + c0);
#pragma unroll
    for (int j = 0; j < 4; ++j) {
        int row = blk * 64 + r0 + j;
        if (row < N) {
            float4 o;
            o.x = fmaxf(acc[j][0] + bb.x, 0.f);
            o.y = fmaxf(acc[j][1] + bb.y, 0.f);
            o.z = fmaxf(acc[j][2] + bb.z, 0.f);
            o.w = fmaxf(acc[j][3] + bb.w, 0.f);
            *(float4*)(out + (size_t)row * FEAT + c0) = o;
        }
    }
}

// ---------- 5. final linear [N,64] @ [64,2] + b, one wave per row ----------
__global__ void final_kernel(const float* __restrict__ h, const float* __restrict__ Wl,
                             const float* __restrict__ bl, void* __restrict__ out,
                             int N, const int* __restrict__ flags) {
    long gid = (long)blockIdx.x * 256 + threadIdx.x;
    int row = (int)(gid >> 6);
    if (row >= N) return;
    int lane = threadIdx.x & 63;
    float v = h[(size_t)row * FEAT + lane];
    float2 w = *(const float2*)(Wl + lane * 2);   // Wl[lane][0..1]
    float p0 = v * w.x;
    float p1 = v * w.y;
#pragma unroll
    for (int off = 32; off > 0; off >>= 1) {
        p0 += __shfl_down(p0, off);
        p1 += __shfl_down(p1, off);
    }
    if (lane == 0) {
        p0 += bl[0];
        p1 += bl[1];
        if (flags[0]) {
            unsigned int o = ((unsigned int)f2bf(p1) << 16) | (unsigned int)f2bf(p0);
            ((unsigned int*)out)[row] = o;
        } else {
            ((float2*)out)[row] = make_float2(p0, p1);
        }
    }
}

extern "C" void kernel_launch(void* const* d_in, const int* in_sizes, int n_in,
                              void* d_out, int out_size, void* d_ws, size_t ws_size,
                              hipStream_t stream) {
    const void* x_in = d_in[0];
    const int*  ei32 = (const int*)d_in[1];

    int N = in_sizes[0] / FEAT;
    int E = in_sizes[1] / 2;

    // workspace layout (floats unless noted)
    float* x32   = (float*)d_ws;                       // N*64
    float* agg   = x32 + (size_t)N * FEAT;             // N*64
    float* h     = agg + (size_t)N * FEAT;             // N*64
    float* w1a32 = h + (size_t)N * FEAT;               // 4096
    float* w1r32 = w1a32 + 4096;                       // 4096
    float* b1_32 = w1r32 + 4096;                       // 64
    float* w2a32 = b1_32 + 64;                         // 4096
    float* w2r32 = w2a32 + 4096;                       // 4096
    float* b2_32 = w2r32 + 4096;                       // 64
    float* wl32  = b2_32 + 64;                         // 128
    float* bl32  = wl32 + 128;                         // 2
    int*   cnt   = (int*)(bl32 + 2);                   // N
    int*   flags = cnt + N;                            // 2

    // 0. detect dtypes (device-side, capture-safe, deterministic)
    detect_kernel<<<1, 256, 0, stream>>>((const unsigned short*)x_in, ei32, flags);

    // 1. convert inputs to fp32 workspace copies
    int n4 = N * FEAT / 4;
    cvt_x_kernel<<<(n4 + 255) / 256, 256, 0, stream>>>(x_in, x32, n4, flags);
    cvt_small_kernel<<<16, 256, 0, stream>>>(d_in[2], w1a32, 4096, flags);
    cvt_small_kernel<<<16, 256, 0, stream>>>(d_in[3], w1r32, 4096, flags);
    cvt_small_kernel<<<1, 256, 0, stream>>>(d_in[4], b1_32, 64, flags);
    cvt_small_kernel<<<16, 256, 0, stream>>>(d_in[5], w2a32, 4096, flags);
    cvt_small_kernel<<<16, 256, 0, stream>>>(d_in[6], w2r32, 4096, flags);
    cvt_small_kernel<<<1, 256, 0, stream>>>(d_in[7], b2_32, 64, flags);
    cvt_small_kernel<<<1, 256, 0, stream>>>(d_in[8], wl32, 128, flags);
    cvt_small_kernel<<<1, 256, 0, stream>>>(d_in[9], bl32, 2, flags);

    // 2. degrees (shared by both layers)
    hipMemsetAsync(cnt, 0, (size_t)N * sizeof(int), stream);
    degree_kernel<<<(E + 255) / 256, 256, 0, stream>>>(ei32, cnt, E, N, flags);

    long totalS = (long)E * 64;
    int sBlocks = (int)((totalS + 255) / 256);
    int gBlocks = (N + 63) / 64;

    // 3. layer 1
    hipMemsetAsync(agg, 0, (size_t)N * FEAT * sizeof(float), stream);
    scatter_kernel<<<sBlocks, 256, 0, stream>>>(x32, ei32, agg, E, N, flags);
    sage_gemm_kernel<<<gBlocks, 256, 0, stream>>>(agg, x32, cnt, w1a32, w1r32, b1_32, h, N);

    // 4. layer 2 (h in place; blocks are row-disjoint, inputs staged to LDS first)
    hipMemsetAsync(agg, 0, (size_t)N * FEAT * sizeof(float), stream);
    scatter_kernel<<<sBlocks, 256, 0, stream>>>(h, ei32, agg, E, N, flags);
    sage_gemm_kernel<<<gBlocks, 256, 0, stream>>>(agg, h, cnt, w2a32, w2r32, b2_32, h, N);

    // 5. output projection
    final_kernel<<<(int)(((long)N * 64 + 255) / 256), 256, 0, stream>>>(h, wl32, bl32, d_out, N, flags);
}

// Round 3
// 528.016 us; speedup vs baseline: 1.8926x; 1.8926x over previous
//
#include <hip/hip_runtime.h>
#include <hip/hip_bf16.h>

#define FEAT 64

// ---------- bf16 helpers ----------
__device__ __forceinline__ float bflo2f(unsigned int u) {
    union { unsigned int u; float f; } v; v.u = u << 16; return v.f;
}
__device__ __forceinline__ float bfhi2f(unsigned int u) {
    union { unsigned int u; float f; } v; v.u = u & 0xffff0000u; return v.f;
}
__device__ __forceinline__ unsigned short f2bf(float f) {
    union { float f; unsigned int u; } v; v.f = f;
    unsigned int u = v.u;
    u += 0x7fffu + ((u >> 16) & 1u);   // round-to-nearest-even
    return (unsigned short)(u >> 16);
}

// ---------- 0. runtime dtype detection ----------
// flags[0] = 1 if float arrays are bf16, 0 if fp32
// flags[1] = 1 if edge_index is int64, 0 if int32
__global__ void detect_kernel(const unsigned short* __restrict__ xh,
                              const int* __restrict__ ei32,
                              int* __restrict__ flags) {
    __shared__ int cnt_bf, cnt_nz;
    int tid = threadIdx.x;
    if (tid == 0) { cnt_bf = 0; cnt_nz = 0; }
    __syncthreads();
    unsigned short h = xh[tid * 2];
    int e = (h >> 7) & 0xFF;
    if (e >= 110 && e <= 132) atomicAdd(&cnt_bf, 1);
    if (ei32[tid * 2 + 1] != 0) atomicAdd(&cnt_nz, 1);
    __syncthreads();
    if (tid == 0) {
        flags[0] = (cnt_bf >= 128) ? 1 : 0;
        flags[1] = (cnt_nz < 8) ? 1 : 0;
    }
}

// ---------- 1. x -> f32 (4 elems/thread, both dtypes) ----------
__global__ void cvt_x_kernel(const void* __restrict__ in, float* __restrict__ out,
                             int n4, const int* __restrict__ flags) {
    int i = blockIdx.x * 256 + threadIdx.x;
    if (i >= n4) return;
    if (flags[0]) {
        uint2 v = ((const uint2*)in)[i];
        float4 o;
        o.x = bflo2f(v.x & 0xffffu); o.y = bfhi2f(v.x);
        o.z = bflo2f(v.y & 0xffffu); o.w = bfhi2f(v.y);
        ((float4*)out)[i] = o;
    } else {
        ((float4*)out)[i] = ((const float4*)in)[i];
    }
}

// ---------- 1b. all weights/biases -> f32, one launch ----------
// out layout: w1a[0,4096) w1r[4096,8192) b1[8192,8256) w2a[8256,12352)
//             w2r[12352,16448) b2[16448,16512) wl[16512,16640) bl[16640,16642)
__global__ void cvt_weights_kernel(const void* __restrict__ w1a, const void* __restrict__ w1r,
                                   const void* __restrict__ b1,  const void* __restrict__ w2a,
                                   const void* __restrict__ w2r, const void* __restrict__ b2,
                                   const void* __restrict__ wl,  const void* __restrict__ bl,
                                   float* __restrict__ out, const int* __restrict__ flags) {
    int i = blockIdx.x * 256 + threadIdx.x;
    if (i >= 16642) return;
    const void* src; int off;
    if      (i < 4096)  { src = w1a; off = i; }
    else if (i < 8192)  { src = w1r; off = i - 4096; }
    else if (i < 8256)  { src = b1;  off = i - 8192; }
    else if (i < 12352) { src = w2a; off = i - 8256; }
    else if (i < 16448) { src = w2r; off = i - 12352; }
    else if (i < 16512) { src = b2;  off = i - 16448; }
    else if (i < 16640) { src = wl;  off = i - 16512; }
    else                { src = bl;  off = i - 16640; }
    out[i] = flags[0] ? bflo2f(((const unsigned short*)src)[off])
                      : ((const float*)src)[off];
}

// ---------- 2. degree histogram (valid src AND dst, matches fill) ----------
__global__ void degree_kernel(const int* __restrict__ ei32, int* __restrict__ cnt,
                              int E, int N, const int* __restrict__ flags) {
    int e = blockIdx.x * 256 + threadIdx.x;
    if (e >= E) return;
    int idx64 = flags[1];
    int s = idx64 ? ei32[2L * e]             : ei32[e];
    int d = idx64 ? ei32[2L * ((long)E + e)] : ei32[(long)E + e];
    if ((unsigned)s >= (unsigned)N || (unsigned)d >= (unsigned)N) return;
    atomicAdd(&cnt[d], 1);
}

// ---------- 3. exclusive scan of cnt -> offs (3 kernels) ----------
// scan1: per-block (2048 items) exclusive scan + block total
__global__ __launch_bounds__(256) void scan1_kernel(const int* __restrict__ cnt,
                                                    int* __restrict__ offs,
                                                    int* __restrict__ blocksum, int N) {
    int tid = threadIdx.x;
    int base = blockIdx.x * 2048 + tid * 8;
    int v[8];
    int tsum = 0;
#pragma unroll
    for (int i = 0; i < 8; ++i) {
        v[i] = (base + i < N) ? cnt[base + i] : 0;
        tsum += v[i];
    }
    int lane = tid & 63;
    int x = tsum;
#pragma unroll
    for (int off = 1; off < 64; off <<= 1) {
        int y = __shfl_up(x, off);
        if (lane >= off) x += y;
    }
    __shared__ int wsum[4];
    int wave = tid >> 6;
    if (lane == 63) wsum[wave] = x;
    __syncthreads();
    int woff = 0;
#pragma unroll
    for (int w = 0; w < 4; ++w) if (w < wave) woff += wsum[w];
    int run = woff + x - tsum;   // exclusive prefix for this thread's chunk
#pragma unroll
    for (int i = 0; i < 8; ++i) {
        if (base + i < N) offs[base + i] = run;
        run += v[i];
    }
    if (tid == 255) blocksum[blockIdx.x] = woff + x;
}

// scan2: tiny serial exclusive scan of block sums (B ~ 49)
__global__ void scan2_kernel(int* __restrict__ blocksum, int B) {
    if (threadIdx.x == 0 && blockIdx.x == 0) {
        int run = 0;
        for (int i = 0; i < B; ++i) { int v = blocksum[i]; blocksum[i] = run; run += v; }
    }
}

// scan3: add block offsets; also materialize head pointers for fill
__global__ void scan3_kernel(int* __restrict__ offs, int* __restrict__ heads,
                             const int* __restrict__ blocksum, int N) {
    int i = blockIdx.x * 256 + threadIdx.x;
    if (i < N) {
        int v = offs[i] + blocksum[i >> 11];
        offs[i] = v;
        heads[i] = v;
    }
}

// ---------- 4. fill CSR source list (order within a node irrelevant: sum commutes) ----------
__global__ void fill_kernel(const int* __restrict__ ei32, int* __restrict__ heads,
                            int* __restrict__ srcs_sorted, int E, int N,
                            const int* __restrict__ flags) {
    int e = blockIdx.x * 256 + threadIdx.x;
    if (e >= E) return;
    int idx64 = flags[1];
    int s = idx64 ? ei32[2L * e]             : ei32[e];
    int d = idx64 ? ei32[2L * ((long)E + e)] : ei32[(long)E + e];
    if ((unsigned)s >= (unsigned)N || (unsigned)d >= (unsigned)N) return;
    int pos = atomicAdd(&heads[d], 1);
    srcs_sorted[pos] = s;
}

// ---------- 5. gather-aggregate: one wave per node, lane = feature ----------
// writes mean directly (agg pre-scaled by 1/deg); no atomics, no memset needed
__global__ __launch_bounds__(256) void aggregate_kernel(
    const float* __restrict__ feat, const int* __restrict__ srcs_sorted,
    const int* __restrict__ offs, const int* __restrict__ cnt,
    float* __restrict__ agg, int N) {
    long gid = (long)blockIdx.x * 256 + threadIdx.x;
    int node = (int)(gid >> 6);
    if (node >= N) return;
    int lane = threadIdx.x & 63;
    int start = offs[node];
    int deg = cnt[node];
    int end = start + deg;
    float acc = 0.f;
    int e = start;
    for (; e + 4 <= end; e += 4) {
        int s0 = srcs_sorted[e + 0];
        int s1 = srcs_sorted[e + 1];
        int s2 = srcs_sorted[e + 2];
        int s3 = srcs_sorted[e + 3];
        float v0 = feat[(size_t)s0 * FEAT + lane];
        float v1 = feat[(size_t)s1 * FEAT + lane];
        float v2 = feat[(size_t)s2 * FEAT + lane];
        float v3 = feat[(size_t)s3 * FEAT + lane];
        acc += v0; acc += v1; acc += v2; acc += v3;
    }
    for (; e < end; ++e)
        acc += feat[(size_t)srcs_sorted[e] * FEAT + lane];
    float inv = 1.0f / (float)(deg > 0 ? deg : 1);
    agg[(size_t)node * FEAT + lane] = acc * inv;
}

// ---------- 6. fused SAGE layer GEMM: out = relu([agg | root] @ [Wa;Wr] + b) ----------
// block = 256 threads, tile = 64 rows x 64 cols, K = 128, all fp32
// W points at contiguous [Wa(64x64); Wr(64x64)] = 8192 floats
__global__ __launch_bounds__(256) void sage_gemm_kernel(
    const float* __restrict__ agg, const float* __restrict__ root,
    const float* __restrict__ W, const float* __restrict__ bias,
    float* __restrict__ out, int N) {

    __shared__ float A_l[64][128];
    __shared__ float B_l[128 * 64];

    int tid = threadIdx.x;
    int blk = blockIdx.x;

    {
        const float4* w4 = (const float4*)W;
        float4* b4 = (float4*)B_l;
#pragma unroll
        for (int i = 0; i < 8; ++i) b4[tid + i * 256] = w4[tid + i * 256];
    }
#pragma unroll
    for (int i = 0; i < 8; ++i) {
        int idx = tid + i * 256;
        int r = idx >> 5;
        int c = idx & 31;
        int row = blk * 64 + r;
        float4 v = make_float4(0.f, 0.f, 0.f, 0.f);
        if (row < N) {
            v = (c < 16) ? *(const float4*)(agg  + (size_t)row * FEAT + c * 4)
                         : *(const float4*)(root + (size_t)row * FEAT + (c - 16) * 4);
        }
        *(float4*)&A_l[r][c * 4] = v;
    }
    __syncthreads();

    int cx = tid & 15;
    int ry = tid >> 4;
    int c0 = cx * 4;
    int r0 = ry * 4;

    float acc[4][4];
#pragma unroll
    for (int j = 0; j < 4; ++j)
#pragma unroll
        for (int i = 0; i < 4; ++i) acc[j][i] = 0.f;

#pragma unroll 8
    for (int k = 0; k < 128; ++k) {
        float4 b = *(const float4*)(B_l + k * 64 + c0);
        float a0 = A_l[r0 + 0][k];
        float a1 = A_l[r0 + 1][k];
        float a2 = A_l[r0 + 2][k];
        float a3 = A_l[r0 + 3][k];
        acc[0][0] += a0 * b.x; acc[0][1] += a0 * b.y; acc[0][2] += a0 * b.z; acc[0][3] += a0 * b.w;
        acc[1][0] += a1 * b.x; acc[1][1] += a1 * b.y; acc[1][2] += a1 * b.z; acc[1][3] += a1 * b.w;
        acc[2][0] += a2 * b.x; acc[2][1] += a2 * b.y; acc[2][2] += a2 * b.z; acc[2][3] += a2 * b.w;
        acc[3][0] += a3 * b.x; acc[3][1] += a3 * b.y; acc[3][2] += a3 * b.z; acc[3][3] += a3 * b.w;
    }

    float4 bb = *(const float4*)(bias + c0);
#pragma unroll
    for (int j = 0; j < 4; ++j) {
        int row = blk * 64 + r0 + j;
        if (row < N) {
            float4 o;
            o.x = fmaxf(acc[j][0] + bb.x, 0.f);
            o.y = fmaxf(acc[j][1] + bb.y, 0.f);
            o.z = fmaxf(acc[j][2] + bb.z, 0.f);
            o.w = fmaxf(acc[j][3] + bb.w, 0.f);
            *(float4*)(out + (size_t)row * FEAT + c0) = o;
        }
    }
}

// ---------- 7. final linear [N,64] @ [64,2] + b, one wave per row ----------
__global__ void final_kernel(const float* __restrict__ h, const float* __restrict__ Wl,
                             const float* __restrict__ bl, void* __restrict__ out,
                             int N, const int* __restrict__ flags) {
    long gid = (long)blockIdx.x * 256 + threadIdx.x;
    int row = (int)(gid >> 6);
    if (row >= N) return;
    int lane = threadIdx.x & 63;
    float v = h[(size_t)row * FEAT + lane];
    float2 w = *(const float2*)(Wl + lane * 2);
    float p0 = v * w.x;
    float p1 = v * w.y;
#pragma unroll
    for (int off = 32; off > 0; off >>= 1) {
        p0 += __shfl_down(p0, off);
        p1 += __shfl_down(p1, off);
    }
    if (lane == 0) {
        p0 += bl[0];
        p1 += bl[1];
        if (flags[0]) {
            unsigned int o = ((unsigned int)f2bf(p1) << 16) | (unsigned int)f2bf(p0);
            ((unsigned int*)out)[row] = o;
        } else {
            ((float2*)out)[row] = make_float2(p0, p1);
        }
    }
}

extern "C" void kernel_launch(void* const* d_in, const int* in_sizes, int n_in,
                              void* d_out, int out_size, void* d_ws, size_t ws_size,
                              hipStream_t stream) {
    const void* x_in = d_in[0];
    const int*  ei32 = (const int*)d_in[1];

    int N = in_sizes[0] / FEAT;
    int E = in_sizes[1] / 2;

    // workspace layout
    float* x32    = (float*)d_ws;                      // N*64
    float* agg    = x32 + (size_t)N * FEAT;            // N*64
    float* h      = agg + (size_t)N * FEAT;            // N*64
    float* wbuf   = h + (size_t)N * FEAT;              // 16642 (see cvt_weights layout)
    float* w1     = wbuf;                              // [w1a;w1r] 8192
    float* b1_32  = wbuf + 8192;                       // 64
    float* w2     = wbuf + 8256;                       // [w2a;w2r] 8192
    float* b2_32  = wbuf + 16448;                      // 64
    float* wl32   = wbuf + 16512;                      // 128
    float* bl32   = wbuf + 16640;                      // 2
    int*   cnt    = (int*)(wbuf + 16704);              // N
    int*   offs   = cnt + N;                           // N
    int*   heads  = offs + N;                          // N
    int*   bsum   = heads + N;                         // <=1024
    int*   flags  = bsum + 1024;                       // 2
    int*   srcs   = flags + 2;                         // E

    // 0. dtype detection (device-side, deterministic, capture-safe)
    detect_kernel<<<1, 256, 0, stream>>>((const unsigned short*)x_in, ei32, flags);

    // 1. convert inputs to fp32
    int n4 = N * FEAT / 4;
    cvt_x_kernel<<<(n4 + 255) / 256, 256, 0, stream>>>(x_in, x32, n4, flags);
    cvt_weights_kernel<<<(16642 + 255) / 256, 256, 0, stream>>>(
        d_in[2], d_in[3], d_in[4], d_in[5], d_in[6], d_in[7], d_in[8], d_in[9], wbuf, flags);

    // 2. CSR build: degree -> scan -> fill
    hipMemsetAsync(cnt, 0, (size_t)N * sizeof(int), stream);
    degree_kernel<<<(E + 255) / 256, 256, 0, stream>>>(ei32, cnt, E, N, flags);
    int nScanBlocks = (N + 2047) / 2048;
    scan1_kernel<<<nScanBlocks, 256, 0, stream>>>(cnt, offs, bsum, N);
    scan2_kernel<<<1, 64, 0, stream>>>(bsum, nScanBlocks);
    scan3_kernel<<<(N + 255) / 256, 256, 0, stream>>>(offs, heads, bsum, N);
    fill_kernel<<<(E + 255) / 256, 256, 0, stream>>>(ei32, heads, srcs, E, N, flags);

    int aBlocks = (int)(((long)N * 64 + 255) / 256);
    int gBlocks = (N + 63) / 64;

    // 3. layer 1
    aggregate_kernel<<<aBlocks, 256, 0, stream>>>(x32, srcs, offs, cnt, agg, N);
    sage_gemm_kernel<<<gBlocks, 256, 0, stream>>>(agg, x32, w1, b1_32, h, N);

    // 4. layer 2 (h in place; blocks row-disjoint, inputs staged via LDS)
    aggregate_kernel<<<aBlocks, 256, 0, stream>>>(h, srcs, offs, cnt, agg, N);
    sage_gemm_kernel<<<gBlocks, 256, 0, stream>>>(agg, h, w2, b2_32, h, N);

    // 5. output projection
    final_kernel<<<aBlocks, 256, 0, stream>>>(h, wl32, bl32, d_out, N, flags);
}

// Round 4
// 362.552 us; speedup vs baseline: 2.7564x; 1.4564x over previous
//
#include <hip/hip_runtime.h>
#include <hip/hip_bf16.h>

#define FEAT 64
#define CHUNK 8192   // edges per P1/P3 block
#define MAX_NB 1024  // max buckets (N <= 262144)

// ---------- bf16 helpers ----------
__device__ __forceinline__ float bflo2f(unsigned int u) {
    union { unsigned int u; float f; } v; v.u = u << 16; return v.f;
}
__device__ __forceinline__ float bfhi2f(unsigned int u) {
    union { unsigned int u; float f; } v; v.u = u & 0xffff0000u; return v.f;
}
__device__ __forceinline__ unsigned short f2bf(float f) {
    union { float f; unsigned int u; } v; v.f = f;
    unsigned int u = v.u;
    u += 0x7fffu + ((u >> 16) & 1u);   // round-to-nearest-even
    return (unsigned short)(u >> 16);
}

// ---------- 0. runtime dtype detection ----------
// flags[0] = 1 if float arrays are bf16, 0 if fp32
// flags[1] = 1 if edge_index is int64, 0 if int32
__global__ void detect_kernel(const unsigned short* __restrict__ xh,
                              const int* __restrict__ ei32,
                              int* __restrict__ flags) {
    __shared__ int cnt_bf, cnt_nz;
    int tid = threadIdx.x;
    if (tid == 0) { cnt_bf = 0; cnt_nz = 0; }
    __syncthreads();
    unsigned short h = xh[tid * 2];
    int e = (h >> 7) & 0xFF;
    if (e >= 110 && e <= 132) atomicAdd(&cnt_bf, 1);
    if (ei32[tid * 2 + 1] != 0) atomicAdd(&cnt_nz, 1);
    __syncthreads();
    if (tid == 0) {
        flags[0] = (cnt_bf >= 128) ? 1 : 0;
        flags[1] = (cnt_nz < 8) ? 1 : 0;
    }
}

// ---------- 1. x -> bf16 workspace copy (8 elems/thread) ----------
__global__ void cvt_x_kernel(const void* __restrict__ in, unsigned short* __restrict__ out16,
                             int n8, const int* __restrict__ flags) {
    int i = blockIdx.x * 256 + threadIdx.x;
    if (i >= n8) return;
    if (flags[0]) {
        ((uint4*)out16)[i] = ((const uint4*)in)[i];   // already bf16: raw copy
    } else {
        float4 a = ((const float4*)in)[2 * i];
        float4 b = ((const float4*)in)[2 * i + 1];
        uint4 o;
        o.x = (unsigned int)f2bf(a.x) | ((unsigned int)f2bf(a.y) << 16);
        o.y = (unsigned int)f2bf(a.z) | ((unsigned int)f2bf(a.w) << 16);
        o.z = (unsigned int)f2bf(b.x) | ((unsigned int)f2bf(b.y) << 16);
        o.w = (unsigned int)f2bf(b.z) | ((unsigned int)f2bf(b.w) << 16);
        ((uint4*)out16)[i] = o;
    }
}

// ---------- 1b. all weights/biases -> f32, one launch ----------
__global__ void cvt_weights_kernel(const void* __restrict__ w1a, const void* __restrict__ w1r,
                                   const void* __restrict__ b1,  const void* __restrict__ w2a,
                                   const void* __restrict__ w2r, const void* __restrict__ b2,
                                   const void* __restrict__ wl,  const void* __restrict__ bl,
                                   float* __restrict__ out, const int* __restrict__ flags) {
    int i = blockIdx.x * 256 + threadIdx.x;
    if (i >= 16642) return;
    const void* src; int off;
    if      (i < 4096)  { src = w1a; off = i; }
    else if (i < 8192)  { src = w1r; off = i - 4096; }
    else if (i < 8256)  { src = b1;  off = i - 8192; }
    else if (i < 12352) { src = w2a; off = i - 8256; }
    else if (i < 16448) { src = w2r; off = i - 12352; }
    else if (i < 16512) { src = b2;  off = i - 16448; }
    else if (i < 16640) { src = wl;  off = i - 16512; }
    else                { src = bl;  off = i - 16640; }
    out[i] = flags[0] ? bflo2f(((const unsigned short*)src)[off])
                      : ((const float*)src)[off];
}

// ---------- P1: per-chunk bucket histogram ----------
// bucket = dst >> 8; hist layout bucket-major: hist[k*EC + chunk]
__global__ __launch_bounds__(256) void p1_hist_kernel(
    const int* __restrict__ ei32, int* __restrict__ hist,
    int E, int N, int NB, int EC, const int* __restrict__ flags) {
    __shared__ int lh[MAX_NB];
    int tid = threadIdx.x, c = blockIdx.x;
    for (int i = tid; i < NB; i += 256) lh[i] = 0;
    __syncthreads();
    int idx64 = flags[1];
    long base = (long)c * CHUNK;
#pragma unroll 4
    for (int j = 0; j < CHUNK / 256; ++j) {
        long e = base + j * 256 + tid;
        if (e < E) {
            int s = idx64 ? ei32[2 * e]             : ei32[e];
            int d = idx64 ? ei32[2 * ((long)E + e)] : ei32[(long)E + e];
            if ((unsigned)s < (unsigned)N && (unsigned)d < (unsigned)N)
                atomicAdd(&lh[d >> 8], 1);
        }
    }
    __syncthreads();
    for (int k = tid; k < NB; k += 256) hist[(long)k * EC + c] = lh[k];
}

// ---------- scan (3 kernels, generic length) ----------
__global__ __launch_bounds__(256) void scan1_kernel(const int* __restrict__ in,
                                                    int* __restrict__ out,
                                                    int* __restrict__ blocksum, int n) {
    int tid = threadIdx.x;
    int base = blockIdx.x * 2048 + tid * 8;
    int v[8];
    int tsum = 0;
#pragma unroll
    for (int i = 0; i < 8; ++i) {
        v[i] = (base + i < n) ? in[base + i] : 0;
        tsum += v[i];
    }
    int lane = tid & 63;
    int x = tsum;
#pragma unroll
    for (int off = 1; off < 64; off <<= 1) {
        int y = __shfl_up(x, off);
        if (lane >= off) x += y;
    }
    __shared__ int wsum[4];
    int wave = tid >> 6;
    if (lane == 63) wsum[wave] = x;
    __syncthreads();
    int woff = 0;
#pragma unroll
    for (int w = 0; w < 4; ++w) if (w < wave) woff += wsum[w];
    int run = woff + x - tsum;
#pragma unroll
    for (int i = 0; i < 8; ++i) {
        if (base + i < n) out[base + i] = run;
        run += v[i];
    }
    if (tid == 255) blocksum[blockIdx.x] = woff + x;
}

__global__ void scan2_kernel(int* __restrict__ blocksum, int B) {
    if (threadIdx.x == 0 && blockIdx.x == 0) {
        int run = 0;
        for (int i = 0; i < B; ++i) { int v = blocksum[i]; blocksum[i] = run; run += v; }
    }
}

__global__ void scan3_kernel(int* __restrict__ out, const int* __restrict__ blocksum, int n) {
    int i = blockIdx.x * 256 + threadIdx.x;
    if (i < n) out[i] += blocksum[i >> 11];
}

// ---------- P3: scatter packed edges into bucket-major order ----------
// packed = src | ((dst & 255) << 20)   (requires N < 2^20)
__global__ __launch_bounds__(256) void p3_scatter_kernel(
    const int* __restrict__ ei32, const int* __restrict__ hscan,
    int* __restrict__ bkt, int E, int N, int NB, int EC,
    const int* __restrict__ flags) {
    __shared__ int lh[MAX_NB];
    int tid = threadIdx.x, c = blockIdx.x;
    for (int i = tid; i < NB; i += 256) lh[i] = 0;
    __syncthreads();
    int idx64 = flags[1];
    long base = (long)c * CHUNK;
#pragma unroll 4
    for (int j = 0; j < CHUNK / 256; ++j) {
        long e = base + j * 256 + tid;
        if (e < E) {
            int s = idx64 ? ei32[2 * e]             : ei32[e];
            int d = idx64 ? ei32[2 * ((long)E + e)] : ei32[(long)E + e];
            if ((unsigned)s < (unsigned)N && (unsigned)d < (unsigned)N) {
                int k = d >> 8;
                int r = atomicAdd(&lh[k], 1);
                bkt[hscan[(long)k * EC + c] + r] = s | ((d & 255) << 20);
            }
        }
    }
}

// ---------- P4: per-bucket CSR finalize (one block per bucket) ----------
__global__ __launch_bounds__(256) void p4_build_kernel(
    const int* __restrict__ bkt, const int* __restrict__ hscan, const int* __restrict__ hist,
    int* __restrict__ offs, int* __restrict__ cnt, int* __restrict__ srcs,
    int E, int N, int NB, int EC) {
    int k = blockIdx.x, tid = threadIdx.x;
    int start = hscan[(long)k * EC];
    int end = (k + 1 < NB) ? hscan[(long)(k + 1) * EC]
                           : (hscan[(long)NB * EC - 1] + hist[(long)NB * EC - 1]);
    __shared__ int lc[256], lheads[256], wsum[4];
    lc[tid] = 0;
    __syncthreads();
    for (int e = start + tid; e < end; e += 256)
        atomicAdd(&lc[(bkt[e] >> 20) & 255], 1);
    __syncthreads();
    int cv = lc[tid];
    int lane = tid & 63, wave = tid >> 6;
    int x = cv;
#pragma unroll
    for (int off = 1; off < 64; off <<= 1) {
        int y = __shfl_up(x, off);
        if (lane >= off) x += y;
    }
    if (lane == 63) wsum[wave] = x;
    __syncthreads();
    int woff = 0;
#pragma unroll
    for (int w = 0; w < 4; ++w) if (w < wave) woff += wsum[w];
    int excl = woff + x - cv;
    int gnode = k * 256 + tid;
    if (gnode < N) { offs[gnode] = start + excl; cnt[gnode] = cv; }
    lheads[tid] = excl;
    __syncthreads();
    for (int e = start + tid; e < end; e += 256) {
        int p = bkt[e];
        int d8 = (p >> 20) & 255;
        int pos = start + atomicAdd(&lheads[d8], 1);
        srcs[pos] = p & 0xFFFFF;
    }
}

// ---------- 5. gather-aggregate (bf16 feat): one wave per node, lane = feature ----------
__global__ __launch_bounds__(256) void aggregate_kernel(
    const unsigned short* __restrict__ feat16, const int* __restrict__ srcs,
    const int* __restrict__ offs, const int* __restrict__ cnt,
    float* __restrict__ agg, int N) {
    long gid = (long)blockIdx.x * 256 + threadIdx.x;
    int node = (int)(gid >> 6);
    if (node >= N) return;
    int lane = threadIdx.x & 63;
    int start = offs[node];
    int deg = cnt[node];
    int end = start + deg;
    float acc = 0.f;
    int e = start;
    for (; e + 4 <= end; e += 4) {
        int s0 = srcs[e + 0];
        int s1 = srcs[e + 1];
        int s2 = srcs[e + 2];
        int s3 = srcs[e + 3];
        float v0 = bflo2f(feat16[(size_t)s0 * FEAT + lane]);
        float v1 = bflo2f(feat16[(size_t)s1 * FEAT + lane]);
        float v2 = bflo2f(feat16[(size_t)s2 * FEAT + lane]);
        float v3 = bflo2f(feat16[(size_t)s3 * FEAT + lane]);
        acc += v0; acc += v1; acc += v2; acc += v3;
    }
    for (; e < end; ++e)
        acc += bflo2f(feat16[(size_t)srcs[e] * FEAT + lane]);
    float inv = 1.0f / (float)(deg > 0 ? deg : 1);
    agg[(size_t)node * FEAT + lane] = acc * inv;
}

// ---------- 6. fused SAGE GEMM: out16 = bf16(relu([agg | root16] @ [Wa;Wr] + b)) ----------
__global__ __launch_bounds__(256) void sage_gemm_kernel(
    const float* __restrict__ agg, const unsigned short* __restrict__ root16,
    const float* __restrict__ W, const float* __restrict__ bias,
    unsigned short* __restrict__ out16, int N) {

    __shared__ float A_l[64][128];
    __shared__ float B_l[128 * 64];

    int tid = threadIdx.x;
    int blk = blockIdx.x;

    {   // stage B = [Wa ; Wr] fp32, 2048 float4
        const float4* w4 = (const float4*)W;
        float4* b4 = (float4*)B_l;
#pragma unroll
        for (int i = 0; i < 8; ++i) b4[tid + i * 256] = w4[tid + i * 256];
    }
    // stage A cols 0..63 = agg (fp32): 1024 float4
#pragma unroll
    for (int i = 0; i < 4; ++i) {
        int idx = tid + i * 256;
        int r = idx >> 4;
        int ch = idx & 15;
        int row = blk * 64 + r;
        float4 v = (row < N) ? *(const float4*)(agg + (size_t)row * FEAT + ch * 4)
                             : make_float4(0.f, 0.f, 0.f, 0.f);
        *(float4*)&A_l[r][ch * 4] = v;
    }
    // stage A cols 64..127 = root16 (bf16): 512 uint4 (8 elems each)
#pragma unroll
    for (int i = 0; i < 2; ++i) {
        int idx = tid + i * 256;
        int r = idx >> 3;
        int ch = idx & 7;
        int row = blk * 64 + r;
        uint4 u = (row < N) ? ((const uint4*)(root16 + (size_t)row * FEAT))[ch]
                            : make_uint4(0, 0, 0, 0);
        float* dstp = &A_l[r][64 + ch * 8];
        dstp[0] = bflo2f(u.x & 0xffffu); dstp[1] = bfhi2f(u.x);
        dstp[2] = bflo2f(u.y & 0xffffu); dstp[3] = bfhi2f(u.y);
        dstp[4] = bflo2f(u.z & 0xffffu); dstp[5] = bfhi2f(u.z);
        dstp[6] = bflo2f(u.w & 0xffffu); dstp[7] = bfhi2f(u.w);
    }
    __syncthreads();

    int cx = tid & 15;
    int ry = tid >> 4;
    int c0 = cx * 4;
    int r0 = ry * 4;

    float acc[4][4];
#pragma unroll
    for (int j = 0; j < 4; ++j)
#pragma unroll
        for (int i = 0; i < 4; ++i) acc[j][i] = 0.f;

#pragma unroll 8
    for (int k = 0; k < 128; ++k) {
        float4 b = *(const float4*)(B_l + k * 64 + c0);
        float a0 = A_l[r0 + 0][k];
        float a1 = A_l[r0 + 1][k];
        float a2 = A_l[r0 + 2][k];
        float a3 = A_l[r0 + 3][k];
        acc[0][0] += a0 * b.x; acc[0][1] += a0 * b.y; acc[0][2] += a0 * b.z; acc[0][3] += a0 * b.w;
        acc[1][0] += a1 * b.x; acc[1][1] += a1 * b.y; acc[1][2] += a1 * b.z; acc[1][3] += a1 * b.w;
        acc[2][0] += a2 * b.x; acc[2][1] += a2 * b.y; acc[2][2] += a2 * b.z; acc[2][3] += a2 * b.w;
        acc[3][0] += a3 * b.x; acc[3][1] += a3 * b.y; acc[3][2] += a3 * b.z; acc[3][3] += a3 * b.w;
    }

    float4 bb = *(const float4*)(bias + c0);
#pragma unroll
    for (int j = 0; j < 4; ++j) {
        int row = blk * 64 + r0 + j;
        if (row < N) {
            float ox = fmaxf(acc[j][0] + bb.x, 0.f);
            float oy = fmaxf(acc[j][1] + bb.y, 0.f);
            float oz = fmaxf(acc[j][2] + bb.z, 0.f);
            float ow = fmaxf(acc[j][3] + bb.w, 0.f);
            uint2 o;
            o.x = (unsigned int)f2bf(ox) | ((unsigned int)f2bf(oy) << 16);
            o.y = (unsigned int)f2bf(oz) | ((unsigned int)f2bf(ow) << 16);
            *(uint2*)(out16 + (size_t)row * FEAT + c0) = o;
        }
    }
}

// ---------- 7. final linear [N,64] @ [64,2] + b, one wave per row ----------
__global__ void final_kernel(const unsigned short* __restrict__ h16, const float* __restrict__ Wl,
                             const float* __restrict__ bl, void* __restrict__ out,
                             int N, const int* __restrict__ flags) {
    long gid = (long)blockIdx.x * 256 + threadIdx.x;
    int row = (int)(gid >> 6);
    if (row >= N) return;
    int lane = threadIdx.x & 63;
    float v = bflo2f(h16[(size_t)row * FEAT + lane]);
    float2 w = *(const float2*)(Wl + lane * 2);
    float p0 = v * w.x;
    float p1 = v * w.y;
#pragma unroll
    for (int off = 32; off > 0; off >>= 1) {
        p0 += __shfl_down(p0, off);
        p1 += __shfl_down(p1, off);
    }
    if (lane == 0) {
        p0 += bl[0];
        p1 += bl[1];
        if (flags[0]) {
            unsigned int o = ((unsigned int)f2bf(p1) << 16) | (unsigned int)f2bf(p0);
            ((unsigned int*)out)[row] = o;
        } else {
            ((float2*)out)[row] = make_float2(p0, p1);
        }
    }
}

extern "C" void kernel_launch(void* const* d_in, const int* in_sizes, int n_in,
                              void* d_out, int out_size, void* d_ws, size_t ws_size,
                              hipStream_t stream) {
    const void* x_in = d_in[0];
    const int*  ei32 = (const int*)d_in[1];

    int N = in_sizes[0] / FEAT;
    int E = in_sizes[1] / 2;
    int NB = (N + 255) >> 8;             // buckets (one block of 256 nodes each)
    int EC = (E + CHUNK - 1) / CHUNK;    // edge chunks
    int HN = NB * EC;                    // hist length

    // workspace layout
    float*          agg   = (float*)d_ws;                               // N*64 f32
    float*          wbuf  = agg + (size_t)N * FEAT;                     // 16704 f32
    unsigned short* x16   = (unsigned short*)(wbuf + 16704);            // N*64 bf16
    unsigned short* h16   = x16 + (size_t)N * FEAT;                     // N*64 bf16
    int*            hist  = (int*)(h16 + (size_t)N * FEAT);             // HN
    int*            hscan = hist + HN;                                  // HN
    int*            bsum  = hscan + HN;                                 // <=1024
    int*            flags = bsum + 1024;                                // 2 (+pad)
    int*            offs  = flags + 16;                                 // N
    int*            cnt   = offs + N;                                   // N
    int*            bkt   = cnt + N;                                    // E
    int*            srcs  = bkt + E;                                    // E

    float* w1    = wbuf;            // [w1a;w1r] 8192
    float* b1_32 = wbuf + 8192;     // 64
    float* w2    = wbuf + 8256;     // [w2a;w2r] 8192
    float* b2_32 = wbuf + 16448;    // 64
    float* wl32  = wbuf + 16512;    // 128
    float* bl32  = wbuf + 16640;    // 2

    // 0. dtype detection
    detect_kernel<<<1, 256, 0, stream>>>((const unsigned short*)x_in, ei32, flags);

    // 1. conversions
    int n8 = N * FEAT / 8;
    cvt_x_kernel<<<(n8 + 255) / 256, 256, 0, stream>>>(x_in, x16, n8, flags);
    cvt_weights_kernel<<<(16642 + 255) / 256, 256, 0, stream>>>(
        d_in[2], d_in[3], d_in[4], d_in[5], d_in[6], d_in[7], d_in[8], d_in[9], wbuf, flags);

    // 2. CSR build: bucket hist -> scan -> bucket scatter -> per-bucket finalize
    p1_hist_kernel<<<EC, 256, 0, stream>>>(ei32, hist, E, N, NB, EC, flags);
    int sB = (HN + 2047) / 2048;
    scan1_kernel<<<sB, 256, 0, stream>>>(hist, hscan, bsum, HN);
    scan2_kernel<<<1, 64, 0, stream>>>(bsum, sB);
    scan3_kernel<<<(HN + 255) / 256, 256, 0, stream>>>(hscan, bsum, HN);
    p3_scatter_kernel<<<EC, 256, 0, stream>>>(ei32, hscan, bkt, E, N, NB, EC, flags);
    p4_build_kernel<<<NB, 256, 0, stream>>>(bkt, hscan, hist, offs, cnt, srcs, E, N, NB, EC);

    int aBlocks = (int)(((long)N * 64 + 255) / 256);
    int gBlocks = (N + 63) / 64;

    // 3. layer 1
    aggregate_kernel<<<aBlocks, 256, 0, stream>>>(x16, srcs, offs, cnt, agg, N);
    sage_gemm_kernel<<<gBlocks, 256, 0, stream>>>(agg, x16, w1, b1_32, h16, N);

    // 4. layer 2 (h16 in place; blocks row-disjoint, staged via LDS)
    aggregate_kernel<<<aBlocks, 256, 0, stream>>>(h16, srcs, offs, cnt, agg, N);
    sage_gemm_kernel<<<gBlocks, 256, 0, stream>>>(agg, h16, w2, b2_32, h16, N);

    // 5. output projection
    final_kernel<<<aBlocks, 256, 0, stream>>>(h16, wl32, bl32, d_out, N, flags);
}

// Round 6
// 282.131 us; speedup vs baseline: 3.5421x; 1.2850x over previous
//
#include <hip/hip_runtime.h>
#include <hip/hip_bf16.h>

#define FEAT 64
#define CHUNK 8192   // edges per P1/P3 block
#define MAX_NB 1024  // max buckets (N <= 262144)

typedef __attribute__((ext_vector_type(8))) short bf16x8;
typedef __attribute__((ext_vector_type(4))) float f32x4;

// ---------- bf16 helpers ----------
__device__ __forceinline__ float bflo2f(unsigned int u) {
    union { unsigned int u; float f; } v; v.u = u << 16; return v.f;
}
__device__ __forceinline__ float bfhi2f(unsigned int u) {
    union { unsigned int u; float f; } v; v.u = u & 0xffff0000u; return v.f;
}
__device__ __forceinline__ unsigned short f2bf(float f) {
    union { float f; unsigned int u; } v; v.f = f;
    unsigned int u = v.u;
    u += 0x7fffu + ((u >> 16) & 1u);   // round-to-nearest-even
    return (unsigned short)(u >> 16);
}

// ---------- 0. runtime dtype detection ----------
__global__ void detect_kernel(const unsigned short* __restrict__ xh,
                              const int* __restrict__ ei32,
                              int* __restrict__ flags) {
    __shared__ int cnt_bf, cnt_nz;
    int tid = threadIdx.x;
    if (tid == 0) { cnt_bf = 0; cnt_nz = 0; }
    __syncthreads();
    unsigned short h = xh[tid * 2];
    int e = (h >> 7) & 0xFF;
    if (e >= 110 && e <= 132) atomicAdd(&cnt_bf, 1);
    if (ei32[tid * 2 + 1] != 0) atomicAdd(&cnt_nz, 1);
    __syncthreads();
    if (tid == 0) {
        flags[0] = (cnt_bf >= 128) ? 1 : 0;
        flags[1] = (cnt_nz < 8) ? 1 : 0;
    }
}

// ---------- 1. x -> bf16 workspace copy ----------
__global__ void cvt_x_kernel(const void* __restrict__ in, unsigned short* __restrict__ out16,
                             int n8, const int* __restrict__ flags) {
    int i = blockIdx.x * 256 + threadIdx.x;
    if (i >= n8) return;
    if (flags[0]) {
        ((uint4*)out16)[i] = ((const uint4*)in)[i];
    } else {
        float4 a = ((const float4*)in)[2 * i];
        float4 b = ((const float4*)in)[2 * i + 1];
        uint4 o;
        o.x = (unsigned int)f2bf(a.x) | ((unsigned int)f2bf(a.y) << 16);
        o.y = (unsigned int)f2bf(a.z) | ((unsigned int)f2bf(a.w) << 16);
        o.z = (unsigned int)f2bf(b.x) | ((unsigned int)f2bf(b.y) << 16);
        o.w = (unsigned int)f2bf(b.z) | ((unsigned int)f2bf(b.w) << 16);
        ((uint4*)out16)[i] = o;
    }
}

// ---------- 1b. weights -> f32 buf + bf16 transposed Wt for MFMA ----------
// wbuf layout: w1[0,8192) b1[8192,8256) w2[8256,16448) b2[16448,16512)
//              wl[16512,16640) bl[16640,16642)
// Wt layout: layer0 [n*128+k] (k<64 from Wa, k>=64 from Wr), layer1 at +8192
__global__ void cvt_weights_kernel(const void* __restrict__ w1a, const void* __restrict__ w1r,
                                   const void* __restrict__ b1,  const void* __restrict__ w2a,
                                   const void* __restrict__ w2r, const void* __restrict__ b2,
                                   const void* __restrict__ wl,  const void* __restrict__ bl,
                                   float* __restrict__ out, unsigned short* __restrict__ Wt,
                                   const int* __restrict__ flags) {
    int i = blockIdx.x * 256 + threadIdx.x;
    if (i >= 16642) return;
    const void* src; int off;
    if      (i < 4096)  { src = w1a; off = i; }
    else if (i < 8192)  { src = w1r; off = i - 4096; }
    else if (i < 8256)  { src = b1;  off = i - 8192; }
    else if (i < 12352) { src = w2a; off = i - 8256; }
    else if (i < 16448) { src = w2r; off = i - 12352; }
    else if (i < 16512) { src = b2;  off = i - 16448; }
    else if (i < 16640) { src = wl;  off = i - 16512; }
    else                { src = bl;  off = i - 16640; }
    float v = flags[0] ? bflo2f(((const unsigned short*)src)[off])
                       : ((const float*)src)[off];
    out[i] = v;
    unsigned short hv = f2bf(v);   // exact round-trip when input was bf16
    if (i < 4096)                      Wt[(off & 63) * 128 + (off >> 6)] = hv;
    else if (i < 8192)                 Wt[(off & 63) * 128 + 64 + (off >> 6)] = hv;
    else if (i >= 8256 && i < 12352)   Wt[8192 + (off & 63) * 128 + (off >> 6)] = hv;
    else if (i >= 12352 && i < 16448)  Wt[8192 + (off & 63) * 128 + 64 + (off >> 6)] = hv;
}

// ---------- P1: per-chunk bucket histogram (bucket = dst >> 8) ----------
__global__ __launch_bounds__(256) void p1_hist_kernel(
    const int* __restrict__ ei32, int* __restrict__ hist,
    int E, int N, int NB, int EC, const int* __restrict__ flags) {
    __shared__ int lh[MAX_NB];
    int tid = threadIdx.x, c = blockIdx.x;
    for (int i = tid; i < NB; i += 256) lh[i] = 0;
    __syncthreads();
    int idx64 = flags[1];
    long base = (long)c * CHUNK;
#pragma unroll 4
    for (int j = 0; j < CHUNK / 256; ++j) {
        long e = base + j * 256 + tid;
        if (e < E) {
            int s = idx64 ? ei32[2 * e]             : ei32[e];
            int d = idx64 ? ei32[2 * ((long)E + e)] : ei32[(long)E + e];
            if ((unsigned)s < (unsigned)N && (unsigned)d < (unsigned)N)
                atomicAdd(&lh[d >> 8], 1);
        }
    }
    __syncthreads();
    for (int k = tid; k < NB; k += 256) hist[(long)k * EC + c] = lh[k];
}

// ---------- scan (3 kernels) ----------
__global__ __launch_bounds__(256) void scan1_kernel(const int* __restrict__ in,
                                                    int* __restrict__ out,
                                                    int* __restrict__ blocksum, int n) {
    int tid = threadIdx.x;
    int base = blockIdx.x * 2048 + tid * 8;
    int v[8];
    int tsum = 0;
#pragma unroll
    for (int i = 0; i < 8; ++i) {
        v[i] = (base + i < n) ? in[base + i] : 0;
        tsum += v[i];
    }
    int lane = tid & 63;
    int x = tsum;
#pragma unroll
    for (int off = 1; off < 64; off <<= 1) {
        int y = __shfl_up(x, off);
        if (lane >= off) x += y;
    }
    __shared__ int wsum[4];
    int wave = tid >> 6;
    if (lane == 63) wsum[wave] = x;
    __syncthreads();
    int woff = 0;
#pragma unroll
    for (int w = 0; w < 4; ++w) if (w < wave) woff += wsum[w];
    int run = woff + x - tsum;
#pragma unroll
    for (int i = 0; i < 8; ++i) {
        if (base + i < n) out[base + i] = run;
        run += v[i];
    }
    if (tid == 255) blocksum[blockIdx.x] = woff + x;
}

__global__ void scan2_kernel(int* __restrict__ blocksum, int B) {
    if (threadIdx.x == 0 && blockIdx.x == 0) {
        int run = 0;
        for (int i = 0; i < B; ++i) { int v = blocksum[i]; blocksum[i] = run; run += v; }
    }
}

__global__ void scan3_kernel(int* __restrict__ out, const int* __restrict__ blocksum, int n) {
    int i = blockIdx.x * 256 + threadIdx.x;
    if (i < n) out[i] += blocksum[i >> 11];
}

// ---------- P3: scatter packed edges into bucket-major order ----------
__global__ __launch_bounds__(256) void p3_scatter_kernel(
    const int* __restrict__ ei32, const int* __restrict__ hscan,
    int* __restrict__ bkt, int E, int N, int NB, int EC,
    const int* __restrict__ flags) {
    __shared__ int lh[MAX_NB];
    int tid = threadIdx.x, c = blockIdx.x;
    for (int i = tid; i < NB; i += 256) lh[i] = 0;
    __syncthreads();
    int idx64 = flags[1];
    long base = (long)c * CHUNK;
#pragma unroll 4
    for (int j = 0; j < CHUNK / 256; ++j) {
        long e = base + j * 256 + tid;
        if (e < E) {
            int s = idx64 ? ei32[2 * e]             : ei32[e];
            int d = idx64 ? ei32[2 * ((long)E + e)] : ei32[(long)E + e];
            if ((unsigned)s < (unsigned)N && (unsigned)d < (unsigned)N) {
                int k = d >> 8;
                int r = atomicAdd(&lh[k], 1);
                bkt[hscan[(long)k * EC + c] + r] = s | ((d & 255) << 20);
            }
        }
    }
}

// ---------- P4: per-bucket CSR finalize ----------
__global__ __launch_bounds__(256) void p4_build_kernel(
    const int* __restrict__ bkt, const int* __restrict__ hscan, const int* __restrict__ hist,
    int* __restrict__ offs, int* __restrict__ cnt, int* __restrict__ srcs,
    int E, int N, int NB, int EC) {
    int k = blockIdx.x, tid = threadIdx.x;
    int start = hscan[(long)k * EC];
    int end = (k + 1 < NB) ? hscan[(long)(k + 1) * EC]
                           : (hscan[(long)NB * EC - 1] + hist[(long)NB * EC - 1]);
    __shared__ int lc[256], lheads[256], wsum[4];
    lc[tid] = 0;
    __syncthreads();
    for (int e = start + tid; e < end; e += 256)
        atomicAdd(&lc[(bkt[e] >> 20) & 255], 1);
    __syncthreads();
    int cv = lc[tid];
    int lane = tid & 63, wave = tid >> 6;
    int x = cv;
#pragma unroll
    for (int off = 1; off < 64; off <<= 1) {
        int y = __shfl_up(x, off);
        if (lane >= off) x += y;
    }
    if (lane == 63) wsum[wave] = x;
    __syncthreads();
    int woff = 0;
#pragma unroll
    for (int w = 0; w < 4; ++w) if (w < wave) woff += wsum[w];
    int excl = woff + x - cv;
    int gnode = k * 256 + tid;
    if (gnode < N) { offs[gnode] = start + excl; cnt[gnode] = cv; }
    lheads[tid] = excl;
    __syncthreads();
    for (int e = start + tid; e < end; e += 256) {
        int p = bkt[e];
        int d8 = (p >> 20) & 255;
        int pos = start + atomicAdd(&lheads[d8], 1);
        srcs[pos] = p & 0xFFFFF;
    }
}

// ---------- 5. gather-aggregate: one wave per node, 2 edges per load ----------
// lanes 0-31 handle even edges, 32-63 odd edges; lane li covers features 2li,2li+1
__global__ __launch_bounds__(256) void aggregate_kernel(
    const unsigned short* __restrict__ feat16, const int* __restrict__ srcs,
    const int* __restrict__ offs, const int* __restrict__ cnt,
    unsigned short* __restrict__ agg16, int N) {
    long gid = (long)blockIdx.x * 256 + threadIdx.x;
    int node = (int)(gid >> 6);
    if (node >= N) return;
    int lane = threadIdx.x & 63;
    int half = lane >> 5;
    int li = lane & 31;
    int start = offs[node];
    int deg = cnt[node];
    int end = start + deg;
    float acc0 = 0.f, acc1 = 0.f;
    int e = start;
    for (; e + 8 <= end; e += 8) {
        int s0 = srcs[e + 0 + half];
        int s1 = srcs[e + 2 + half];
        int s2 = srcs[e + 4 + half];
        int s3 = srcs[e + 6 + half];
        unsigned u0 = *(const unsigned*)(feat16 + (size_t)s0 * FEAT + 2 * li);
        unsigned u1 = *(const unsigned*)(feat16 + (size_t)s1 * FEAT + 2 * li);
        unsigned u2 = *(const unsigned*)(feat16 + (size_t)s2 * FEAT + 2 * li);
        unsigned u3 = *(const unsigned*)(feat16 + (size_t)s3 * FEAT + 2 * li);
        acc0 += bflo2f(u0 & 0xffffu); acc1 += bfhi2f(u0);
        acc0 += bflo2f(u1 & 0xffffu); acc1 += bfhi2f(u1);
        acc0 += bflo2f(u2 & 0xffffu); acc1 += bfhi2f(u2);
        acc0 += bflo2f(u3 & 0xffffu); acc1 += bfhi2f(u3);
    }
    for (; e < end; e += 2) {
        int idx = e + half;
        int s = srcs[idx < end ? idx : end - 1];
        unsigned u = *(const unsigned*)(feat16 + (size_t)s * FEAT + 2 * li);
        if (idx < end) { acc0 += bflo2f(u & 0xffffu); acc1 += bfhi2f(u); }
    }
    acc0 += __shfl_xor(acc0, 32);
    acc1 += __shfl_xor(acc1, 32);
    if (half == 0) {
        float inv = 1.0f / (float)(deg > 0 ? deg : 1);
        unsigned o = (unsigned)f2bf(acc0 * inv) | ((unsigned)f2bf(acc1 * inv) << 16);
        *(unsigned*)(agg16 + (size_t)node * FEAT + 2 * li) = o;
    }
}

// ---------- 6. MFMA SAGE GEMM: out16 = bf16(relu([agg16|root16] @ Wt^T + b)) ----------
// 256 thr = 4 waves; wave w -> rows 16w..16w+15, cols 0..63; 16x16x32 bf16 MFMA
// if wl != null: fused final projection out_final[row][0..1]
__global__ __launch_bounds__(256) void sage_gemm_kernel(
    const unsigned short* __restrict__ agg16, const unsigned short* __restrict__ root16,
    const unsigned short* __restrict__ Wt, const float* __restrict__ bias,
    unsigned short* __restrict__ out16, int N,
    const float* __restrict__ wl, const float* __restrict__ bl,
    void* __restrict__ out_final, const int* __restrict__ flags) {

    __shared__ unsigned short A_l[64][136];   // stride 68 dwords -> 2-way (free)
    __shared__ unsigned short B_l[64][136];   // Wt[n][k]

    int tid = threadIdx.x;
    int blk = blockIdx.x;

    // stage B: 1024 chunks of 8 shorts (B is 64 rows x 128 k)
#pragma unroll
    for (int i = 0; i < 4; ++i) {
        int ch = tid + i * 256;
        int n = ch >> 4, kc = ch & 15;
        *(uint4*)&B_l[n][kc * 8] = *(const uint4*)(Wt + n * 128 + kc * 8);
    }
    // stage A: rows = [agg16 | root16] (64 rows x 128 k)
#pragma unroll
    for (int i = 0; i < 4; ++i) {
        int ch = tid + i * 256;
        int r = ch >> 4, c = ch & 15;
        int row = blk * 64 + r;
        uint4 u = make_uint4(0, 0, 0, 0);
        if (row < N)
            u = (c < 8) ? ((const uint4*)(agg16 + (size_t)row * FEAT))[c]
                        : ((const uint4*)(root16 + (size_t)row * FEAT))[c - 8];
        *(uint4*)&A_l[r][c * 8] = u;
    }
    __syncthreads();

    int lane = tid & 63;
    int wave = tid >> 6;
    int r0 = wave * 16;
    int m = lane & 15, quad = lane >> 4;

    f32x4 acc0 = {0.f, 0.f, 0.f, 0.f};
    f32x4 acc1 = acc0, acc2 = acc0, acc3 = acc0;

#pragma unroll
    for (int k0 = 0; k0 < 128; k0 += 32) {
        bf16x8 a = *(const bf16x8*)&A_l[r0 + m][k0 + quad * 8];
        bf16x8 b0 = *(const bf16x8*)&B_l[ 0 + m][k0 + quad * 8];
        bf16x8 b1 = *(const bf16x8*)&B_l[16 + m][k0 + quad * 8];
        bf16x8 b2 = *(const bf16x8*)&B_l[32 + m][k0 + quad * 8];
        bf16x8 b3 = *(const bf16x8*)&B_l[48 + m][k0 + quad * 8];
        acc0 = __builtin_amdgcn_mfma_f32_16x16x32_bf16(a, b0, acc0, 0, 0, 0);
        acc1 = __builtin_amdgcn_mfma_f32_16x16x32_bf16(a, b1, acc1, 0, 0, 0);
        acc2 = __builtin_amdgcn_mfma_f32_16x16x32_bf16(a, b2, acc2, 0, 0, 0);
        acc3 = __builtin_amdgcn_mfma_f32_16x16x32_bf16(a, b3, acc3, 0, 0, 0);
    }
    __syncthreads();   // done reading A_l; reuse as C staging

    // epilogue: +bias, relu, bf16 -> A_l[row][col]  (C/D: col=lane&15, row=quad*4+reg)
#pragma unroll
    for (int c = 0; c < 4; ++c) {
        f32x4 av = (c == 0) ? acc0 : (c == 1) ? acc1 : (c == 2) ? acc2 : acc3;
        float bv = bias[c * 16 + m];
#pragma unroll
        for (int reg = 0; reg < 4; ++reg) {
            float v = fmaxf(av[reg] + bv, 0.f);
            A_l[r0 + quad * 4 + reg][c * 16 + m] = f2bf(v);
        }
    }
    __syncthreads();

    // coalesced store of C rows: C is 64 rows x 64 cols = 512 uint4 chunks
    // (FIX vs round 5: was 1024 chunks / 16 per row, overflowing each 64-short row)
#pragma unroll
    for (int i = 0; i < 2; ++i) {
        int ch = tid + i * 256;
        int r = ch >> 3, c = ch & 7;
        int row = blk * 64 + r;
        if (row < N)
            ((uint4*)(out16 + (size_t)row * FEAT))[c] = *(const uint4*)&A_l[r][c * 8];
    }

    // fused final projection (layer 2): 4 threads per row, 16 feats each
    if (wl) {
        int r = tid >> 2, part = tid & 3;
        int row = blk * 64 + r;
        if (row < N) {
            float p0 = 0.f, p1 = 0.f;
#pragma unroll
            for (int j = 0; j < 16; ++j) {
                int f = part * 16 + j;
                float v = bflo2f(A_l[r][f]);
                p0 += v * wl[f * 2 + 0];
                p1 += v * wl[f * 2 + 1];
            }
            p0 += __shfl_down(p0, 2, 4); p0 += __shfl_down(p0, 1, 4);
            p1 += __shfl_down(p1, 2, 4); p1 += __shfl_down(p1, 1, 4);
            if (part == 0) {
                p0 += bl[0];
                p1 += bl[1];
                if (flags[0]) {
                    unsigned int o = ((unsigned int)f2bf(p1) << 16) | (unsigned int)f2bf(p0);
                    ((unsigned int*)out_final)[row] = o;
                } else {
                    ((float2*)out_final)[row] = make_float2(p0, p1);
                }
            }
        }
    }
}

extern "C" void kernel_launch(void* const* d_in, const int* in_sizes, int n_in,
                              void* d_out, int out_size, void* d_ws, size_t ws_size,
                              hipStream_t stream) {
    const void* x_in = d_in[0];
    const int*  ei32 = (const int*)d_in[1];

    int N = in_sizes[0] / FEAT;
    int E = in_sizes[1] / 2;
    int NB = (N + 255) >> 8;
    int EC = (E + CHUNK - 1) / CHUNK;
    int HN = NB * EC;

    // workspace layout
    unsigned short* x16   = (unsigned short*)d_ws;                 // N*64 bf16
    unsigned short* h16   = x16 + (size_t)N * FEAT;                // N*64
    unsigned short* agg16 = h16 + (size_t)N * FEAT;                // N*64
    unsigned short* Wt    = agg16 + (size_t)N * FEAT;              // 16384
    float*          wbuf  = (float*)(Wt + 16384);                  // 16704
    int*            hist  = (int*)(wbuf + 16704);                  // HN
    int*            hscan = hist + HN;                             // HN
    int*            bsum  = hscan + HN;                            // <=1024
    int*            flags = bsum + 1024;                           // 16
    int*            offs  = flags + 16;                            // N
    int*            cnt   = offs + N;                              // N
    int*            bkt   = cnt + N;                               // E
    int*            srcs  = bkt + E;                               // E

    float* b1_32 = wbuf + 8192;
    float* b2_32 = wbuf + 16448;
    float* wl32  = wbuf + 16512;
    float* bl32  = wbuf + 16640;

    // 0. dtype detection
    detect_kernel<<<1, 256, 0, stream>>>((const unsigned short*)x_in, ei32, flags);

    // 1. conversions
    int n8 = N * FEAT / 8;
    cvt_x_kernel<<<(n8 + 255) / 256, 256, 0, stream>>>(x_in, x16, n8, flags);
    cvt_weights_kernel<<<(16642 + 255) / 256, 256, 0, stream>>>(
        d_in[2], d_in[3], d_in[4], d_in[5], d_in[6], d_in[7], d_in[8], d_in[9],
        wbuf, Wt, flags);

    // 2. CSR build
    p1_hist_kernel<<<EC, 256, 0, stream>>>(ei32, hist, E, N, NB, EC, flags);
    int sB = (HN + 2047) / 2048;
    scan1_kernel<<<sB, 256, 0, stream>>>(hist, hscan, bsum, HN);
    scan2_kernel<<<1, 64, 0, stream>>>(bsum, sB);
    scan3_kernel<<<(HN + 255) / 256, 256, 0, stream>>>(hscan, bsum, HN);
    p3_scatter_kernel<<<EC, 256, 0, stream>>>(ei32, hscan, bkt, E, N, NB, EC, flags);
    p4_build_kernel<<<NB, 256, 0, stream>>>(bkt, hscan, hist, offs, cnt, srcs, E, N, NB, EC);

    int aBlocks = (int)(((long)N * 64 + 255) / 256);
    int gBlocks = (N + 63) / 64;

    // 3. layer 1
    aggregate_kernel<<<aBlocks, 256, 0, stream>>>(x16, srcs, offs, cnt, agg16, N);
    sage_gemm_kernel<<<gBlocks, 256, 0, stream>>>(agg16, x16, Wt, b1_32, h16, N,
                                                  nullptr, nullptr, nullptr, flags);

    // 4. layer 2 + fused final projection
    aggregate_kernel<<<aBlocks, 256, 0, stream>>>(h16, srcs, offs, cnt, agg16, N);
    sage_gemm_kernel<<<gBlocks, 256, 0, stream>>>(agg16, h16, Wt + 8192, b2_32, h16, N,
                                                  wl32, bl32, d_out, flags);
}

// Round 7
// 261.908 us; speedup vs baseline: 3.8156x; 1.0772x over previous
//
#include <hip/hip_runtime.h>
#include <hip/hip_bf16.h>

#define FEAT 64
#define CHUNK 8192   // edges per P1/P3 block
#define MAX_NB 1024  // max buckets (N <= 262144)

typedef __attribute__((ext_vector_type(8))) short bf16x8;
typedef __attribute__((ext_vector_type(4))) float f32x4;

// ---------- bf16 helpers ----------
__device__ __forceinline__ float bflo2f(unsigned int u) {
    union { unsigned int u; float f; } v; v.u = u << 16; return v.f;
}
__device__ __forceinline__ float bfhi2f(unsigned int u) {
    union { unsigned int u; float f; } v; v.u = u & 0xffff0000u; return v.f;
}
__device__ __forceinline__ unsigned short f2bf(float f) {
    union { float f; unsigned int u; } v; v.f = f;
    unsigned int u = v.u;
    u += 0x7fffu + ((u >> 16) & 1u);   // round-to-nearest-even
    return (unsigned short)(u >> 16);
}

// ---------- 0. runtime dtype detection ----------
__global__ void detect_kernel(const unsigned short* __restrict__ xh,
                              const int* __restrict__ ei32,
                              int* __restrict__ flags) {
    __shared__ int cnt_bf, cnt_nz;
    int tid = threadIdx.x;
    if (tid == 0) { cnt_bf = 0; cnt_nz = 0; }
    __syncthreads();
    unsigned short h = xh[tid * 2];
    int e = (h >> 7) & 0xFF;
    if (e >= 110 && e <= 132) atomicAdd(&cnt_bf, 1);
    if (ei32[tid * 2 + 1] != 0) atomicAdd(&cnt_nz, 1);
    __syncthreads();
    if (tid == 0) {
        flags[0] = (cnt_bf >= 128) ? 1 : 0;
        flags[1] = (cnt_nz < 8) ? 1 : 0;
    }
}

// ---------- 1. x -> bf16 workspace copy (only needed for fp32 inputs) ----------
__global__ void cvt_x_kernel(const void* __restrict__ in, unsigned short* __restrict__ out16,
                             int n8, const int* __restrict__ flags) {
    if (flags[0]) return;   // bf16 input: kernels read x_in directly
    int i = blockIdx.x * 256 + threadIdx.x;
    if (i >= n8) return;
    float4 a = ((const float4*)in)[2 * i];
    float4 b = ((const float4*)in)[2 * i + 1];
    uint4 o;
    o.x = (unsigned int)f2bf(a.x) | ((unsigned int)f2bf(a.y) << 16);
    o.y = (unsigned int)f2bf(a.z) | ((unsigned int)f2bf(a.w) << 16);
    o.z = (unsigned int)f2bf(b.x) | ((unsigned int)f2bf(b.y) << 16);
    o.w = (unsigned int)f2bf(b.z) | ((unsigned int)f2bf(b.w) << 16);
    ((uint4*)out16)[i] = o;
}

// ---------- 1b. weights -> f32 buf + bf16 transposed Wt for MFMA ----------
// wbuf layout: w1[0,8192) b1[8192,8256) w2[8256,16448) b2[16448,16512)
//              wl[16512,16640) bl[16640,16642)
// Wt layout: layer0 [n*128+k] (k<64 from Wa, k>=64 from Wr), layer1 at +8192
__global__ void cvt_weights_kernel(const void* __restrict__ w1a, const void* __restrict__ w1r,
                                   const void* __restrict__ b1,  const void* __restrict__ w2a,
                                   const void* __restrict__ w2r, const void* __restrict__ b2,
                                   const void* __restrict__ wl,  const void* __restrict__ bl,
                                   float* __restrict__ out, unsigned short* __restrict__ Wt,
                                   const int* __restrict__ flags) {
    int i = blockIdx.x * 256 + threadIdx.x;
    if (i >= 16642) return;
    const void* src; int off;
    if      (i < 4096)  { src = w1a; off = i; }
    else if (i < 8192)  { src = w1r; off = i - 4096; }
    else if (i < 8256)  { src = b1;  off = i - 8192; }
    else if (i < 12352) { src = w2a; off = i - 8256; }
    else if (i < 16448) { src = w2r; off = i - 12352; }
    else if (i < 16512) { src = b2;  off = i - 16448; }
    else if (i < 16640) { src = wl;  off = i - 16512; }
    else                { src = bl;  off = i - 16640; }
    float v = flags[0] ? bflo2f(((const unsigned short*)src)[off])
                       : ((const float*)src)[off];
    out[i] = v;
    unsigned short hv = f2bf(v);   // exact round-trip when input was bf16
    if (i < 4096)                      Wt[(off & 63) * 128 + (off >> 6)] = hv;
    else if (i < 8192)                 Wt[(off & 63) * 128 + 64 + (off >> 6)] = hv;
    else if (i >= 8256 && i < 12352)   Wt[8192 + (off & 63) * 128 + (off >> 6)] = hv;
    else if (i >= 12352 && i < 16448)  Wt[8192 + (off & 63) * 128 + 64 + (off >> 6)] = hv;
}

// ---------- P1: per-chunk bucket histogram (bucket = dst >> 8; dst-only read) ----------
__global__ __launch_bounds__(256) void p1_hist_kernel(
    const int* __restrict__ ei32, int* __restrict__ hist,
    int E, int N, int NB, int EC, const int* __restrict__ flags) {
    __shared__ int lh[MAX_NB];
    int tid = threadIdx.x, c = blockIdx.x;
    for (int i = tid; i < NB; i += 256) lh[i] = 0;
    __syncthreads();
    int idx64 = flags[1];
    long base = (long)c * CHUNK;
#pragma unroll 4
    for (int j = 0; j < CHUNK / 256; ++j) {
        long e = base + j * 256 + tid;
        if (e < E) {
            int d = idx64 ? ei32[2 * ((long)E + e)] : ei32[(long)E + e];
            if ((unsigned)d < (unsigned)N)
                atomicAdd(&lh[d >> 8], 1);
        }
    }
    __syncthreads();
    for (int k = tid; k < NB; k += 256) hist[(long)k * EC + c] = lh[k];
}

// ---------- scan (2 kernels; block-sum prefix folded into scan3) ----------
__global__ __launch_bounds__(256) void scan1_kernel(const int* __restrict__ in,
                                                    int* __restrict__ out,
                                                    int* __restrict__ blocksum, int n) {
    int tid = threadIdx.x;
    int base = blockIdx.x * 2048 + tid * 8;
    int v[8];
    int tsum = 0;
#pragma unroll
    for (int i = 0; i < 8; ++i) {
        v[i] = (base + i < n) ? in[base + i] : 0;
        tsum += v[i];
    }
    int lane = tid & 63;
    int x = tsum;
#pragma unroll
    for (int off = 1; off < 64; off <<= 1) {
        int y = __shfl_up(x, off);
        if (lane >= off) x += y;
    }
    __shared__ int wsum[4];
    int wave = tid >> 6;
    if (lane == 63) wsum[wave] = x;
    __syncthreads();
    int woff = 0;
#pragma unroll
    for (int w = 0; w < 4; ++w) if (w < wave) woff += wsum[w];
    int run = woff + x - tsum;
#pragma unroll
    for (int i = 0; i < 8; ++i) {
        if (base + i < n) out[base + i] = run;
        run += v[i];
    }
    if (tid == 255) blocksum[blockIdx.x] = woff + x;
}

// scan3: add serial prefix of blocksums (<=~40 entries, block-uniform loop)
__global__ void scan3_kernel(int* __restrict__ out, const int* __restrict__ blocksum, int n) {
    int i = blockIdx.x * 256 + threadIdx.x;
    if (i >= n) return;
    int nb = i >> 11;
    int pre = 0;
    for (int b = 0; b < nb; ++b) pre += blocksum[b];
    out[i] += pre;
}

// ---------- P3: scatter packed edges into bucket-major order ----------
// packed = src | ((dst & 255) << 20)   (requires N < 2^20)
__global__ __launch_bounds__(256) void p3_scatter_kernel(
    const int* __restrict__ ei32, const int* __restrict__ hscan,
    int* __restrict__ bkt, int E, int N, int NB, int EC,
    const int* __restrict__ flags) {
    __shared__ int lh[MAX_NB];
    int tid = threadIdx.x, c = blockIdx.x;
    for (int i = tid; i < NB; i += 256) lh[i] = 0;
    __syncthreads();
    int idx64 = flags[1];
    long base = (long)c * CHUNK;
#pragma unroll 4
    for (int j = 0; j < CHUNK / 256; ++j) {
        long e = base + j * 256 + tid;
        if (e < E) {
            int s = idx64 ? ei32[2 * e]             : ei32[e];
            int d = idx64 ? ei32[2 * ((long)E + e)] : ei32[(long)E + e];
            if ((unsigned)d < (unsigned)N) {
                if ((unsigned)s >= (unsigned)N) s = 0;   // clamp (memory safety; inputs are valid)
                int k = d >> 8;
                int r = atomicAdd(&lh[k], 1);
                bkt[hscan[(long)k * EC + c] + r] = s | ((d & 255) << 20);
            }
        }
    }
}

// ---------- P4: per-bucket CSR finalize ----------
__global__ __launch_bounds__(256) void p4_build_kernel(
    const int* __restrict__ bkt, const int* __restrict__ hscan, const int* __restrict__ hist,
    int* __restrict__ offs, int* __restrict__ cnt, int* __restrict__ srcs,
    int E, int N, int NB, int EC) {
    int k = blockIdx.x, tid = threadIdx.x;
    int start = hscan[(long)k * EC];
    int end = (k + 1 < NB) ? hscan[(long)(k + 1) * EC]
                           : (hscan[(long)NB * EC - 1] + hist[(long)NB * EC - 1]);
    __shared__ int lc[256], lheads[256], wsum[4];
    lc[tid] = 0;
    __syncthreads();
    for (int e = start + tid; e < end; e += 256)
        atomicAdd(&lc[(bkt[e] >> 20) & 255], 1);
    __syncthreads();
    int cv = lc[tid];
    int lane = tid & 63, wave = tid >> 6;
    int x = cv;
#pragma unroll
    for (int off = 1; off < 64; off <<= 1) {
        int y = __shfl_up(x, off);
        if (lane >= off) x += y;
    }
    if (lane == 63) wsum[wave] = x;
    __syncthreads();
    int woff = 0;
#pragma unroll
    for (int w = 0; w < 4; ++w) if (w < wave) woff += wsum[w];
    int excl = woff + x - cv;
    int gnode = k * 256 + tid;
    if (gnode < N) { offs[gnode] = start + excl; cnt[gnode] = cv; }
    lheads[tid] = excl;
    __syncthreads();
    for (int e = start + tid; e < end; e += 256) {
        int p = bkt[e];
        int d8 = (p >> 20) & 255;
        int pos = start + atomicAdd(&lheads[d8], 1);
        srcs[pos] = p & 0xFFFFF;
    }
}

// ---------- 5. gather-aggregate: one wave per node, 8 edges per load instr ----------
// 8 groups of 8 lanes; group g handles edge e+g; lane covers feats 8*(lane&7)..+7 (uint4)
__global__ __launch_bounds__(256) void aggregate_kernel(
    const void* __restrict__ feat_raw, const unsigned short* __restrict__ feat_ws,
    const int* __restrict__ srcs,
    const int* __restrict__ offs, const int* __restrict__ cnt,
    unsigned short* __restrict__ agg16, int N, const int* __restrict__ flags) {
    const unsigned short* feat16 = flags[0] ? (const unsigned short*)feat_raw : feat_ws;
    long gid = (long)blockIdx.x * 256 + threadIdx.x;
    int node = (int)(gid >> 6);
    if (node >= N) return;
    int lane = threadIdx.x & 63;
    int g = lane >> 3;         // edge group
    int li = lane & 7;         // feature chunk: 8*li .. 8*li+7
    int start = offs[node];
    int deg = cnt[node];
    int end = start + deg;
    float acc[8] = {0.f, 0.f, 0.f, 0.f, 0.f, 0.f, 0.f, 0.f};
    int e = start;
    // main: 16 edges per iter, 2 uint4 loads in flight
    for (; e + 16 <= end; e += 16) {
        int s0 = srcs[e + g];
        int s1 = srcs[e + 8 + g];
        uint4 u0 = *(const uint4*)(feat16 + (size_t)s0 * FEAT + 8 * li);
        uint4 u1 = *(const uint4*)(feat16 + (size_t)s1 * FEAT + 8 * li);
        acc[0] += bflo2f(u0.x & 0xffffu); acc[1] += bfhi2f(u0.x);
        acc[2] += bflo2f(u0.y & 0xffffu); acc[3] += bfhi2f(u0.y);
        acc[4] += bflo2f(u0.z & 0xffffu); acc[5] += bfhi2f(u0.z);
        acc[6] += bflo2f(u0.w & 0xffffu); acc[7] += bfhi2f(u0.w);
        acc[0] += bflo2f(u1.x & 0xffffu); acc[1] += bfhi2f(u1.x);
        acc[2] += bflo2f(u1.y & 0xffffu); acc[3] += bfhi2f(u1.y);
        acc[4] += bflo2f(u1.z & 0xffffu); acc[5] += bfhi2f(u1.z);
        acc[6] += bflo2f(u1.w & 0xffffu); acc[7] += bfhi2f(u1.w);
    }
    // tail: 8-edge granule, predicated
    for (; e < end; e += 8) {
        int idx = e + g;
        bool ok = idx < end;
        int s = srcs[ok ? idx : end - 1];      // end-1 >= start here (deg > 0)
        uint4 u = *(const uint4*)(feat16 + (size_t)s * FEAT + 8 * li);
        if (ok) {
            acc[0] += bflo2f(u.x & 0xffffu); acc[1] += bfhi2f(u.x);
            acc[2] += bflo2f(u.y & 0xffffu); acc[3] += bfhi2f(u.y);
            acc[4] += bflo2f(u.z & 0xffffu); acc[5] += bfhi2f(u.z);
            acc[6] += bflo2f(u.w & 0xffffu); acc[7] += bfhi2f(u.w);
        }
    }
    // reduce across the 8 edge-groups (lanes differing in bits 3..5)
#pragma unroll
    for (int i = 0; i < 8; ++i) {
        acc[i] += __shfl_xor(acc[i], 8);
        acc[i] += __shfl_xor(acc[i], 16);
        acc[i] += __shfl_xor(acc[i], 32);
    }
    if (g == 0) {
        float inv = 1.0f / (float)(deg > 0 ? deg : 1);
        uint4 o;
        o.x = (unsigned)f2bf(acc[0] * inv) | ((unsigned)f2bf(acc[1] * inv) << 16);
        o.y = (unsigned)f2bf(acc[2] * inv) | ((unsigned)f2bf(acc[3] * inv) << 16);
        o.z = (unsigned)f2bf(acc[4] * inv) | ((unsigned)f2bf(acc[5] * inv) << 16);
        o.w = (unsigned)f2bf(acc[6] * inv) | ((unsigned)f2bf(acc[7] * inv) << 16);
        *(uint4*)(agg16 + (size_t)node * FEAT + 8 * li) = o;
    }
}

// ---------- 6. MFMA SAGE GEMM: out16 = bf16(relu([agg16|root16] @ Wt^T + b)) ----------
// 256 thr = 4 waves; wave w -> rows 16w..16w+15, cols 0..63; 16x16x32 bf16 MFMA
// if wl != null: fused final projection out_final[row][0..1]
__global__ __launch_bounds__(256) void sage_gemm_kernel(
    const unsigned short* __restrict__ agg16,
    const void* __restrict__ root_raw, const unsigned short* __restrict__ root_ws,
    const unsigned short* __restrict__ Wt, const float* __restrict__ bias,
    unsigned short* __restrict__ out16, int N,
    const float* __restrict__ wl, const float* __restrict__ bl,
    void* __restrict__ out_final, const int* __restrict__ flags, int root_sel) {

    const unsigned short* root16 =
        (root_sel && !flags[0]) ? root_ws : (const unsigned short*)root_raw;

    __shared__ unsigned short A_l[64][136];   // stride 68 dwords -> 2-way (free)
    __shared__ unsigned short B_l[64][136];   // Wt[n][k]

    int tid = threadIdx.x;
    int blk = blockIdx.x;

    // stage B: 1024 chunks of 8 shorts (B is 64 rows x 128 k)
#pragma unroll
    for (int i = 0; i < 4; ++i) {
        int ch = tid + i * 256;
        int n = ch >> 4, kc = ch & 15;
        *(uint4*)&B_l[n][kc * 8] = *(const uint4*)(Wt + n * 128 + kc * 8);
    }
    // stage A: rows = [agg16 | root16] (64 rows x 128 k)
#pragma unroll
    for (int i = 0; i < 4; ++i) {
        int ch = tid + i * 256;
        int r = ch >> 4, c = ch & 15;
        int row = blk * 64 + r;
        uint4 u = make_uint4(0, 0, 0, 0);
        if (row < N)
            u = (c < 8) ? ((const uint4*)(agg16 + (size_t)row * FEAT))[c]
                        : ((const uint4*)(root16 + (size_t)row * FEAT))[c - 8];
        *(uint4*)&A_l[r][c * 8] = u;
    }
    __syncthreads();

    int lane = tid & 63;
    int wave = tid >> 6;
    int r0 = wave * 16;
    int m = lane & 15, quad = lane >> 4;

    f32x4 acc0 = {0.f, 0.f, 0.f, 0.f};
    f32x4 acc1 = acc0, acc2 = acc0, acc3 = acc0;

#pragma unroll
    for (int k0 = 0; k0 < 128; k0 += 32) {
        bf16x8 a = *(const bf16x8*)&A_l[r0 + m][k0 + quad * 8];
        bf16x8 b0 = *(const bf16x8*)&B_l[ 0 + m][k0 + quad * 8];
        bf16x8 b1 = *(const bf16x8*)&B_l[16 + m][k0 + quad * 8];
        bf16x8 b2 = *(const bf16x8*)&B_l[32 + m][k0 + quad * 8];
        bf16x8 b3 = *(const bf16x8*)&B_l[48 + m][k0 + quad * 8];
        acc0 = __builtin_amdgcn_mfma_f32_16x16x32_bf16(a, b0, acc0, 0, 0, 0);
        acc1 = __builtin_amdgcn_mfma_f32_16x16x32_bf16(a, b1, acc1, 0, 0, 0);
        acc2 = __builtin_amdgcn_mfma_f32_16x16x32_bf16(a, b2, acc2, 0, 0, 0);
        acc3 = __builtin_amdgcn_mfma_f32_16x16x32_bf16(a, b3, acc3, 0, 0, 0);
    }
    __syncthreads();   // done reading A_l; reuse as C staging

    // epilogue: +bias, relu, bf16 -> A_l[row][col]  (C/D: col=lane&15, row=quad*4+reg)
#pragma unroll
    for (int c = 0; c < 4; ++c) {
        f32x4 av = (c == 0) ? acc0 : (c == 1) ? acc1 : (c == 2) ? acc2 : acc3;
        float bv = bias[c * 16 + m];
#pragma unroll
        for (int reg = 0; reg < 4; ++reg) {
            float v = fmaxf(av[reg] + bv, 0.f);
            A_l[r0 + quad * 4 + reg][c * 16 + m] = f2bf(v);
        }
    }
    __syncthreads();

    // coalesced store of C rows: C is 64 rows x 64 cols = 512 uint4 chunks
#pragma unroll
    for (int i = 0; i < 2; ++i) {
        int ch = tid + i * 256;
        int r = ch >> 3, c = ch & 7;
        int row = blk * 64 + r;
        if (row < N)
            ((uint4*)(out16 + (size_t)row * FEAT))[c] = *(const uint4*)&A_l[r][c * 8];
    }

    // fused final projection (layer 2): 4 threads per row, 16 feats each
    if (wl) {
        int r = tid >> 2, part = tid & 3;
        int row = blk * 64 + r;
        if (row < N) {
            float p0 = 0.f, p1 = 0.f;
#pragma unroll
            for (int j = 0; j < 16; ++j) {
                int f = part * 16 + j;
                float v = bflo2f(A_l[r][f]);
                p0 += v * wl[f * 2 + 0];
                p1 += v * wl[f * 2 + 1];
            }
            p0 += __shfl_down(p0, 2, 4); p0 += __shfl_down(p0, 1, 4);
            p1 += __shfl_down(p1, 2, 4); p1 += __shfl_down(p1, 1, 4);
            if (part == 0) {
                p0 += bl[0];
                p1 += bl[1];
                if (flags[0]) {
                    unsigned int o = ((unsigned int)f2bf(p1) << 16) | (unsigned int)f2bf(p0);
                    ((unsigned int*)out_final)[row] = o;
                } else {
                    ((float2*)out_final)[row] = make_float2(p0, p1);
                }
            }
        }
    }
}

extern "C" void kernel_launch(void* const* d_in, const int* in_sizes, int n_in,
                              void* d_out, int out_size, void* d_ws, size_t ws_size,
                              hipStream_t stream) {
    const void* x_in = d_in[0];
    const int*  ei32 = (const int*)d_in[1];

    int N = in_sizes[0] / FEAT;
    int E = in_sizes[1] / 2;
    int NB = (N + 255) >> 8;
    int EC = (E + CHUNK - 1) / CHUNK;
    int HN = NB * EC;

    // workspace layout
    unsigned short* x16   = (unsigned short*)d_ws;                 // N*64 bf16 (fp32-input path only)
    unsigned short* h16   = x16 + (size_t)N * FEAT;                // N*64
    unsigned short* agg16 = h16 + (size_t)N * FEAT;                // N*64
    unsigned short* Wt    = agg16 + (size_t)N * FEAT;              // 16384
    float*          wbuf  = (float*)(Wt + 16384);                  // 16704
    int*            hist  = (int*)(wbuf + 16704);                  // HN
    int*            hscan = hist + HN;                             // HN
    int*            bsum  = hscan + HN;                            // <=1024
    int*            flags = bsum + 1024;                           // 16
    int*            offs  = flags + 16;                            // N
    int*            cnt   = offs + N;                              // N
    int*            bkt   = cnt + N;                               // E
    int*            srcs  = bkt + E;                               // E

    float* b1_32 = wbuf + 8192;
    float* b2_32 = wbuf + 16448;
    float* wl32  = wbuf + 16512;
    float* bl32  = wbuf + 16640;

    // 0. dtype detection
    detect_kernel<<<1, 256, 0, stream>>>((const unsigned short*)x_in, ei32, flags);

    // 1. conversions
    int n8 = N * FEAT / 8;
    cvt_x_kernel<<<(n8 + 255) / 256, 256, 0, stream>>>(x_in, x16, n8, flags);
    cvt_weights_kernel<<<(16642 + 255) / 256, 256, 0, stream>>>(
        d_in[2], d_in[3], d_in[4], d_in[5], d_in[6], d_in[7], d_in[8], d_in[9],
        wbuf, Wt, flags);

    // 2. CSR build
    p1_hist_kernel<<<EC, 256, 0, stream>>>(ei32, hist, E, N, NB, EC, flags);
    int sB = (HN + 2047) / 2048;
    scan1_kernel<<<sB, 256, 0, stream>>>(hist, hscan, bsum, HN);
    scan3_kernel<<<(HN + 255) / 256, 256, 0, stream>>>(hscan, bsum, HN);
    p3_scatter_kernel<<<EC, 256, 0, stream>>>(ei32, hscan, bkt, E, N, NB, EC, flags);
    p4_build_kernel<<<NB, 256, 0, stream>>>(bkt, hscan, hist, offs, cnt, srcs, E, N, NB, EC);

    int aBlocks = (int)(((long)N * 64 + 255) / 256);
    int gBlocks = (N + 63) / 64;

    // 3. layer 1 (x read directly from input when bf16)
    aggregate_kernel<<<aBlocks, 256, 0, stream>>>(x_in, x16, srcs, offs, cnt, agg16, N, flags);
    sage_gemm_kernel<<<gBlocks, 256, 0, stream>>>(agg16, x_in, x16, Wt, b1_32, h16, N,
                                                  nullptr, nullptr, nullptr, flags, 1);

    // 4. layer 2 + fused final projection
    aggregate_kernel<<<aBlocks, 256, 0, stream>>>(h16, h16, srcs, offs, cnt, agg16, N, flags);
    sage_gemm_kernel<<<gBlocks, 256, 0, stream>>>(agg16, h16, h16, Wt + 8192, b2_32, h16, N,
                                                  wl32, bl32, d_out, flags, 0);
}